// Round 11
// baseline (207.113 us; speedup 1.0000x reference)
//
#include <hip/hip_runtime.h>
#include <math.h>
#include <stdint.h>

#define HH   48
#define RSW  25            // u32 words per packed-bf16 matrix row (24 data + 1 pad)
#define MATW (HH*RSW)      // 1200 u32 per 48x48 matrix

#define EPSF     1e-6f
#define INVF     0.54132327f          // log(exp(1-1e-6)-1)
#define LOG1MEPS (-1.0000005e-6f)     // log(1-1e-6)

static __device__ __forceinline__ float fexp(float x){ return __expf(x); }
static __device__ __forceinline__ float flog(float x){ return __logf(x); }
static __device__ __forceinline__ float frcp(float x){
  float r = __builtin_amdgcn_rcpf(x);
  return r * (2.0f - x * r);          // 1 Newton step; args finite & positive at call sites
}
static __device__ __forceinline__ float wred_max(float v){
#pragma unroll
  for (int m = 32; m; m >>= 1) v = fmaxf(v, __shfl_xor(v, m, 64));
  return v;
}
static __device__ __forceinline__ float wred_sum(float v){
#pragma unroll
  for (int m = 32; m; m >>= 1) v += __shfl_xor(v, m, 64);
  return v;
}
static __device__ __forceinline__ float fsoftplus(float z){
  return fmaxf(z, 0.0f) + flog(1.0f + fexp(-fabsf(z)));
}
static __device__ __forceinline__ uint32_t bf16_rne(float x){
  uint32_t u = __float_as_uint(x);
  return (u + 0x7fffu + ((u >> 16) & 1u)) >> 16;
}
static __device__ __forceinline__ float bf_lo(uint32_t w){ return __uint_as_float(w << 16); }
static __device__ __forceinline__ float bf_hi(uint32_t w){ return __uint_as_float(w & 0xffff0000u); }

// Stage c = exp(w)-1 (packed bf16 pairs): sum_j exp(w+v) = E + sum_j c*exp(v), E = sum exp(v).
template<int NT>
static __device__ __forceinline__ void init_cmats(uint32_t* CW,
    const float* __restrict__ w_mid, const float* __restrict__ u_last, int tid){
  for (int w = tid; w < 4*HH*24; w += NT){
    int m   = w / (HH*24);
    int rem = w - m*(HH*24);
    int r   = rem / 24, t = rem - r*24;
    const float* src = (m < 3) ? (w_mid + m*HH*HH + r*HH + 2*t)
                               : (u_last + r*HH + 2*t);
    uint32_t b0 = bf16_rne(fexp(src[0]) - 1.0f);
    uint32_t b1 = bf16_rne(fexp(src[1]) - 1.0f);
    CW[m*MATW + r*RSW + t] = b0 | (b1 << 16);
  }
}

// sigmoid via E = exp(-|ps|) <= 1 (no overflow, no clamp); reuse E for log1p in S.
#define SIGMOID_FROM_E(ps, E, R) ( ((ps) >= 0.0f) ? (R) : (E)*(R) )

// ---------------- kernel 1: x-chain (s=0 only), 16 blocks x 4 waves, wave per b ----
__global__ __launch_bounds__(256) void dsf_xchain(
    const float* __restrict__ params, const float* __restrict__ xin,
    const float* __restrict__ w_mid, const float* __restrict__ u_last,
    const float* __restrict__ w_last, float* __restrict__ ws,
    float* __restrict__ out_x)
{
  __shared__ uint32_t CW[4*MATW];
  __shared__ float4 pk[4][HH];

  init_cmats<256>(CW, w_mid, u_last, threadIdx.x);
  __syncthreads();   // only barrier needed: CW is read-only after this; pk is per-wave

  const int wid  = threadIdx.x >> 6;
  const int lane = threadIdx.x & 63;
  const int b    = (blockIdx.x << 2) + wid;
  const bool act = lane < HH;
  const int jj   = act ? lane : (HH-1);
  const float* p = params + (size_t)b * 256 * 768;   // s = 0 row
  float4* mypk = pk[wid];

  float X  = xin[b];
  float xn = 0.0f;

#pragma unroll
  for (int L = 0; L < 3; ++L){
    const float* q = p + L*192;
    float d0 = q[jj], d1 = q[HH+jj], d2 = q[2*HH+jj];
    float a  = fsoftplus(d0 + INVF) + EPSF;
    float ps = fmaf(a, X, d1);
    float ap = fabsf(ps);
    float E  = fexp(-ap);
    float R  = frcp(1.0f + E);
    float sg = SIGMOID_FROM_E(ps, E, R);
    float e  = act ? fexp(d2) : 0.0f;
    float E0 = wred_sum(e);
    float E1 = wred_sum(e * sg);
    if (act) mypk[lane] = make_float4(e, e*sg, 0.0f, 0.0f);
    float t0 = E0, t1 = E1;
    const uint32_t* Cr = CW + L*MATW + jj*RSW;
#pragma unroll
    for (int t = 0; t < 24; ++t){
      uint32_t cw = Cr[t];
      float c0 = bf_lo(cw), c1 = bf_hi(cw);
      float4 q0 = mypk[2*t], q1 = mypk[2*t+1];
      t0 = fmaf(c0, q0.x, fmaf(c1, q1.x, t0));
      t1 = fmaf(c0, q0.y, fmaf(c1, q1.y, t1));
    }
    float xp = fminf(fmaxf(t1 * frcp(t0), 0.0f), 1.0f);
    float xc = fmaf(xp, 1.0f - EPSF, 0.5f*EPSF);
    xn = flog(xc * frcp(1.0f - xc));           // log(xc)-log(1-xc), single log
    if (L == 0){ X = wred_sum(act ? xn : 0.0f); if (lane == 0) ws[b] = X; }
    else if (L == 1){ X = wred_sum(act ? xn : 0.0f); if (lane == 0) ws[64 + b] = X; }
    else { if (act) ws[128 + b*HH + lane] = xn; }
  }

  // last layer: x output only
  const float* q = p + 3*192;
  float d0 = q[jj], d1 = q[HH+jj], d2 = q[2*HH+jj], d3 = q[3*HH+jj];
  float e3 = act ? fexp(d3) : 0.0f;
  float E30 = wred_sum(e3);
  float E31 = wred_sum(e3 * xn);
  if (act) mypk[lane] = make_float4(e3, e3*xn, 0.0f, 0.0f);
  float s0 = E30, s1 = E31;
  const uint32_t* Ur = CW + 3*MATW + jj*RSW;
#pragma unroll
  for (int t = 0; t < 24; ++t){
    uint32_t cw = Ur[t];
    float c0 = bf_lo(cw), c1 = bf_hi(cw);
    float4 q0 = mypk[2*t], q1 = mypk[2*t+1];
    s0 = fmaf(c0, q0.x, fmaf(c1, q1.x, s0));
    s1 = fmaf(c0, q0.y, fmaf(c1, q1.y, s1));
  }
  float dotx = s1 * frcp(s0);
  float a  = fsoftplus(d0 + INVF) + EPSF;
  float ps = fmaf(a, dotx, d1);
  float ap = fabsf(ps);
  float E  = fexp(-ap);
  float R  = frcp(1.0f + E);
  float sg = SIGMOID_FROM_E(ps, E, R);
  float pw = w_last[jj] + d2;
  float ew = act ? fexp(pw) : 0.0f;
  float Z  = wred_sum(ew);
  float xp = fminf(fmaxf(wred_sum(ew * sg) * frcp(Z), 0.0f), 1.0f);
  float xc = fmaf(xp, 1.0f - EPSF, 0.5f*EPSF);
  if (lane == 0) out_x[b] = flog(xc * frcp(1.0f - xc));
}

// ---------------- kernel 2: logdet, one wave per (b,s), 8 waves/block -------------
// 8-wave blocks: round-9 counters showed ~4 blocks/CU resident regardless of LDS
// math -> 4-wave blocks capped at 16 waves/CU (49% occ). 8 waves/block -> 32/CU.
// pk is per-wave ([wid]) so NO per-layer barriers are needed; only the post-init one.
__global__ __launch_bounds__(512) void dsf_logdet(
    const float* __restrict__ params, const float* __restrict__ xin,
    const float* __restrict__ w_mid, const float* __restrict__ u_last,
    const float* __restrict__ w_last, const float* __restrict__ ws,
    float* __restrict__ out_ld)
{
  __shared__ uint32_t CW[4*MATW];   // 19200 B
  __shared__ float4 pk[8][HH];      // 6144 B
  __shared__ float wl[HH];          // ~25.5 KB total; 4 blocks/CU = 102 KB, 32 waves

  init_cmats<512>(CW, w_mid, u_last, threadIdx.x);
  if (threadIdx.x < HH) wl[threadIdx.x] = w_last[threadIdx.x];
  __syncthreads();

  const int wid  = threadIdx.x >> 6;
  const int lane = threadIdx.x & 63;
  const int gw   = (blockIdx.x << 3) + wid;   // b*256 + s
  const int b    = gw >> 8;                   // 8 | 256 -> all waves in block share b
  const bool act = lane < HH;
  const int jj   = act ? lane : (HH-1);
  const float* p = params + (size_t)gw * 768;
  float4* mypk = pk[wid];

  const float Xarr[3] = { xin[b], ws[b], ws[64 + b] };
  float ld = 0.0f;   // lane r holds logdet entry r

#pragma unroll
  for (int L = 0; L < 3; ++L){
    const float* q = p + L*192;
    float d0 = q[jj], d1 = q[HH+jj], d2 = q[2*HH+jj];
    float a  = fsoftplus(d0 + INVF) + EPSF;
    float ps = fmaf(a, Xarr[L], d1);
    float ap = fabsf(ps);
    float E  = fexp(-ap);                 // shared by sigmoid and S (log1p term)
    float R  = frcp(1.0f + E);
    float sg = SIGMOID_FROM_E(ps, E, R);
    // S = logsig(ps)+logsig(-ps)+logc(a) = -ap - 2*log(1+E) + 2eps + log(a)
    float S  = -ap - 2.0f*flog(1.0f + E) + 2.0f*EPSF + flog(a);
    float Ms = wred_max(act ? (d2 + S) : -INFINITY);   // S ~ -300 possible: keep max-sub
    float e  = act ? fexp(d2) : 0.0f;
    float f2 = act ? fexp(d2 + S - Ms) : 0.0f;
    float E0 = wred_sum(e);
    float E1 = wred_sum(e * sg);
    float E2 = wred_sum(f2);
    if (act) mypk[lane] = make_float4(e, e*sg, f2, 0.0f);
    float t0 = E0, t1 = E1, t2 = E2;
    const uint32_t* Cr = CW + L*MATW + jj*RSW;
#pragma unroll
    for (int t = 0; t < 24; ++t){
      uint32_t cw = Cr[t];
      float c0 = bf_lo(cw), c1 = bf_hi(cw);
      float4 q0 = mypk[2*t], q1 = mypk[2*t+1];
      t0 = fmaf(c0, q0.x, fmaf(c1, q1.x, t0));
      t1 = fmaf(c0, q0.y, fmaf(c1, q1.y, t1));
      t2 = fmaf(c0, q0.z, fmaf(c1, q1.z, t2));
    }
    float xp   = fminf(fmaxf(t1 * frcp(t0), 0.0f), 1.0f);
    float xc   = fmaf(xp, 1.0f - EPSF, 0.5f*EPSF);
    float lsum = flog(xc * (1.0f - xc));          // log(xc)+log(1-xc), single log
    float lj2  = Ms + flog(t2 * frcp(t0));        // LSE_j(logsm_w + S), single log
    float lsep = 0.0f;
    if (L > 0){
      float mp = wred_max(act ? ld : -INFINITY);
      float sm = wred_sum(act ? fexp(ld - mp) : 0.0f);
      lsep = mp + flog(sm);
    }
    ld = lj2 + LOG1MEPS - lsum + lsep;
  }

  // ---- last layer ----
  {
    const float* q = p + 3*192;
    float d0 = q[jj], d1 = q[HH+jj], d2 = q[2*HH+jj], d3 = q[3*HH+jj];
    float e3 = act ? fexp(d3) : 0.0f;
    float xv = ws[128 + b*HH + jj];
    float E30 = wred_sum(e3);
    float E31 = wred_sum(e3 * xv);
    if (act) mypk[lane] = make_float4(e3, e3*xv, 0.0f, 0.0f);
    float s0 = E30, s1 = E31;
    const uint32_t* Ur = CW + 3*MATW + jj*RSW;
#pragma unroll
    for (int t = 0; t < 24; ++t){
      uint32_t cw = Ur[t];
      float c0 = bf_lo(cw), c1 = bf_hi(cw);
      float4 q0 = mypk[2*t], q1 = mypk[2*t+1];
      s0 = fmaf(c0, q0.x, fmaf(c1, q1.x, s0));
      s1 = fmaf(c0, q0.y, fmaf(c1, q1.y, s1));
    }
    float dotx = s1 * frcp(s0);
    float lseu = flog(s0);                    // LSE_k(u[r,k]+d3[k])
    float a  = fsoftplus(d0 + INVF) + EPSF;
    float ps = fmaf(a, dotx, d1);
    float ap = fabsf(ps);
    float E  = fexp(-ap);
    float R  = frcp(1.0f + E);
    float sg = SIGMOID_FROM_E(ps, E, R);
    float Sp = -ap - 2.0f*flog(1.0f + E) + 2.0f*EPSF + flog(a);
    float pw = wl[jj] + d2;
    float ew = act ? fexp(pw) : 0.0f;
    float Z  = wred_sum(ew);
    float xp = fminf(fmaxf(wred_sum(ew * sg) * frcp(Z), 0.0f), 1.0f);
    float lsew = flog(Z);
    float xc   = fmaf(xp, 1.0f - EPSF, 0.5f*EPSF);
    float lsum = flog(xc * (1.0f - xc));
    // c_j = logsm_w[j] + Sp_j - lseu_j ; logj2[k] = d3_k + LSE_j(c_j + u[j,k])
    float c  = (pw - lsew) + Sp - lseu;
    float Mc = wred_max(act ? c : -INFINITY);
    float ec = act ? fexp(c - Mc) : 0.0f;
    float Ec = wred_sum(ec);
    if (act) mypk[lane].x = ec;   // same-wave write; ec depends on s0 -> ordered after reads
    // transposed matvec: lane k: acc = Ec + sum_j ec_j * cU[j][k]
    const uint32_t sh = (jj & 1) ? 0u : 16u;
    const int kw = jj >> 1;
    float acc = Ec;
#pragma unroll 8
    for (int j = 0; j < HH; ++j){
      uint32_t cw = CW[3*MATW + j*RSW + kw];
      float cc = __uint_as_float((cw << sh) & 0xffff0000u);
      acc = fmaf(mypk[j].x, cc, acc);
    }
    float lj2k = d3 + Mc + flog(acc);
    float tot  = act ? (lj2k + LOG1MEPS - lsum + ld) : -INFINITY;
    float Mt = wred_max(tot);
    float sm = wred_sum(act ? fexp(tot - Mt) : 0.0f);
    if (lane == 0) out_ld[gw] = Mt + flog(sm);
  }
}

extern "C" void kernel_launch(void* const* d_in, const int* in_sizes, int n_in,
                              void* d_out, int out_size, void* d_ws, size_t ws_size,
                              hipStream_t stream) {
  const float* params = (const float*)d_in[0];   // (64,256,768)
  const float* xin    = (const float*)d_in[1];   // (64,1)
  // d_in[2] = u_mid: provably unused (softmax over size-1 axis)
  const float* w_mid  = (const float*)d_in[3];   // (3,48,48)
  const float* u_last = (const float*)d_in[4];   // (48,48)
  const float* w_last = (const float*)d_in[5];   // (1,48)
  float* out = (float*)d_out;                    // [64 x] ++ [64*256 logdet]
  float* ws  = (float*)d_ws;                     // [64 X1][64 X2][64*48 xvec2]

  hipLaunchKernelGGL(dsf_xchain, dim3(16), dim3(256), 0, stream,
                     params, xin, w_mid, u_last, w_last, ws, out);
  hipLaunchKernelGGL(dsf_logdet, dim3(2048), dim3(512), 0, stream,
                     params, xin, w_mid, u_last, w_last, ws, out + 64);
}

// Round 12
// 178.152 us; speedup vs baseline: 1.1626x; 1.1626x over previous
//
#include <hip/hip_runtime.h>
#include <math.h>
#include <stdint.h>

#define HH   48
#define RSW  25            // u32 words per packed-bf16 matrix row (24 data + 1 pad)
#define MATW (HH*RSW)      // 1200 u32 per 48x48 matrix

#define EPSF     1e-6f
#define INVF     0.54132327f          // log(exp(1-1e-6)-1)
#define LOG1MEPS (-1.0000005e-6f)     // log(1-1e-6)

static __device__ __forceinline__ float fexp(float x){ return __expf(x); }
static __device__ __forceinline__ float flog(float x){ return __logf(x); }
static __device__ __forceinline__ float frcp(float x){
  float r = __builtin_amdgcn_rcpf(x);
  return r * (2.0f - x * r);          // 1 Newton step; args finite & positive at call sites
}
static __device__ __forceinline__ float wred_max(float v){
#pragma unroll
  for (int m = 32; m; m >>= 1) v = fmaxf(v, __shfl_xor(v, m, 64));
  return v;
}
static __device__ __forceinline__ float wred_sum(float v){
#pragma unroll
  for (int m = 32; m; m >>= 1) v += __shfl_xor(v, m, 64);
  return v;
}
static __device__ __forceinline__ float fsoftplus(float z){
  return fmaxf(z, 0.0f) + flog(1.0f + fexp(-fabsf(z)));
}
static __device__ __forceinline__ uint32_t bf16_rne(float x){
  uint32_t u = __float_as_uint(x);
  return (u + 0x7fffu + ((u >> 16) & 1u)) >> 16;
}
static __device__ __forceinline__ float bf_lo(uint32_t w){ return __uint_as_float(w << 16); }
static __device__ __forceinline__ float bf_hi(uint32_t w){ return __uint_as_float(w & 0xffff0000u); }

// Stage c = exp(w)-1 (packed bf16 pairs): sum_j exp(w+v) = E + sum_j c*exp(v), E = sum exp(v).
template<int NT>
static __device__ __forceinline__ void init_cmats(uint32_t* CW,
    const float* __restrict__ w_mid, const float* __restrict__ u_last, int tid){
  for (int w = tid; w < 4*HH*24; w += NT){
    int m   = w / (HH*24);
    int rem = w - m*(HH*24);
    int r   = rem / 24, t = rem - r*24;
    const float* src = (m < 3) ? (w_mid + m*HH*HH + r*HH + 2*t)
                               : (u_last + r*HH + 2*t);
    uint32_t b0 = bf16_rne(fexp(src[0]) - 1.0f);
    uint32_t b1 = bf16_rne(fexp(src[1]) - 1.0f);
    CW[m*MATW + r*RSW + t] = b0 | (b1 << 16);
  }
}

// sigmoid via E = exp(-|ps|) <= 1 (no overflow, no clamp); reuse E for log(1+E) in S.
#define SIGMOID_FROM_E(ps, E, R) ( ((ps) >= 0.0f) ? (R) : (E)*(R) )

// ---------------- kernel 1: x-chain (s=0 only), 16 blocks x 4 waves, wave per b ----
__global__ __launch_bounds__(256) void dsf_xchain(
    const float* __restrict__ params, const float* __restrict__ xin,
    const float* __restrict__ w_mid, const float* __restrict__ u_last,
    const float* __restrict__ w_last, float* __restrict__ ws,
    float* __restrict__ out_x)
{
  __shared__ uint32_t CW[4*MATW];
  __shared__ float4 pk[4][HH];

  init_cmats<256>(CW, w_mid, u_last, threadIdx.x);
  __syncthreads();

  const int wid  = threadIdx.x >> 6;
  const int lane = threadIdx.x & 63;
  const int b    = (blockIdx.x << 2) + wid;
  const bool act = lane < HH;
  const int jj   = act ? lane : (HH-1);
  const float* p = params + (size_t)b * 256 * 768;   // s = 0 row
  float4* mypk = pk[wid];

  float X  = xin[b];
  float xn = 0.0f;

#pragma unroll
  for (int L = 0; L < 3; ++L){
    const float* q = p + L*192;
    float d0 = q[jj], d1 = q[HH+jj], d2 = q[2*HH+jj];
    float a  = fsoftplus(d0 + INVF) + EPSF;
    float ps = fmaf(a, X, d1);
    float ap = fabsf(ps);
    float E  = fexp(-ap);
    float R  = frcp(1.0f + E);
    float sg = SIGMOID_FROM_E(ps, E, R);
    float e  = act ? fexp(d2) : 0.0f;
    float E0 = wred_sum(e);
    float E1 = wred_sum(e * sg);
    if (act) mypk[lane] = make_float4(e, e*sg, 0.0f, 0.0f);
    __syncthreads();   // scheduler fence: keeps VGPR pressure bounded (r11: removal -> 120 VGPR)
    float t0 = E0, t1 = E1;
    const uint32_t* Cr = CW + L*MATW + jj*RSW;
#pragma unroll
    for (int t = 0; t < 24; ++t){
      uint32_t cw = Cr[t];
      float c0 = bf_lo(cw), c1 = bf_hi(cw);
      float4 q0 = mypk[2*t], q1 = mypk[2*t+1];
      t0 = fmaf(c0, q0.x, fmaf(c1, q1.x, t0));
      t1 = fmaf(c0, q0.y, fmaf(c1, q1.y, t1));
    }
    __syncthreads();
    float xp = fminf(fmaxf(t1 * frcp(t0), 0.0f), 1.0f);
    float xc = fmaf(xp, 1.0f - EPSF, 0.5f*EPSF);
    xn = flog(xc * frcp(1.0f - xc));           // log(xc)-log(1-xc), single log
    if (L == 0){ X = wred_sum(act ? xn : 0.0f); if (lane == 0) ws[b] = X; }
    else if (L == 1){ X = wred_sum(act ? xn : 0.0f); if (lane == 0) ws[64 + b] = X; }
    else { if (act) ws[128 + b*HH + lane] = xn; }
  }

  // last layer: x output only
  const float* q = p + 3*192;
  float d0 = q[jj], d1 = q[HH+jj], d2 = q[2*HH+jj], d3 = q[3*HH+jj];
  float e3 = act ? fexp(d3) : 0.0f;
  float E30 = wred_sum(e3);
  float E31 = wred_sum(e3 * xn);
  if (act) mypk[lane] = make_float4(e3, e3*xn, 0.0f, 0.0f);
  __syncthreads();
  float s0 = E30, s1 = E31;
  const uint32_t* Ur = CW + 3*MATW + jj*RSW;
#pragma unroll
  for (int t = 0; t < 24; ++t){
    uint32_t cw = Ur[t];
    float c0 = bf_lo(cw), c1 = bf_hi(cw);
    float4 q0 = mypk[2*t], q1 = mypk[2*t+1];
    s0 = fmaf(c0, q0.x, fmaf(c1, q1.x, s0));
    s1 = fmaf(c0, q0.y, fmaf(c1, q1.y, s1));
  }
  float dotx = s1 * frcp(s0);
  float a  = fsoftplus(d0 + INVF) + EPSF;
  float ps = fmaf(a, dotx, d1);
  float ap = fabsf(ps);
  float E  = fexp(-ap);
  float R  = frcp(1.0f + E);
  float sg = SIGMOID_FROM_E(ps, E, R);
  float pw = w_last[jj] + d2;
  float ew = act ? fexp(pw) : 0.0f;
  float Z  = wred_sum(ew);
  float xp = fminf(fmaxf(wred_sum(ew * sg) * frcp(Z), 0.0f), 1.0f);
  float xc = fmaf(xp, 1.0f - EPSF, 0.5f*EPSF);
  if (lane == 0) out_x[b] = flog(xc * frcp(1.0f - xc));
}

// ---------------- kernel 2: logdet, one wave per (b,s), 4 waves/block -------------
// Round-9 structure (4-wave/256-thr, per-layer barriers, no min-waves bound) + the
// transcendental diet only. r11 showed: removing barriers / 8-wave blocks -> compiler
// pipelines across layers, VGPR 48->120, occupancy 49->21%, dur +27%. Barriers stay.
__global__ __launch_bounds__(256) void dsf_logdet(
    const float* __restrict__ params, const float* __restrict__ xin,
    const float* __restrict__ w_mid, const float* __restrict__ u_last,
    const float* __restrict__ w_last, const float* __restrict__ ws,
    float* __restrict__ out_ld)
{
  __shared__ uint32_t CW[4*MATW];   // 19200 B
  __shared__ float4 pk[4][HH];      // 3072 B
  __shared__ float wl[HH];          // ~22.5 KB total

  init_cmats<256>(CW, w_mid, u_last, threadIdx.x);
  if (threadIdx.x < HH) wl[threadIdx.x] = w_last[threadIdx.x];
  __syncthreads();

  const int wid  = threadIdx.x >> 6;
  const int lane = threadIdx.x & 63;
  const int gw   = (blockIdx.x << 2) + wid;   // b*256 + s
  const int b    = gw >> 8;
  const bool act = lane < HH;
  const int jj   = act ? lane : (HH-1);
  const float* p = params + (size_t)gw * 768;
  float4* mypk = pk[wid];

  const float Xarr[3] = { xin[b], ws[b], ws[64 + b] };
  float ld = 0.0f;   // lane r holds logdet entry r

#pragma unroll
  for (int L = 0; L < 3; ++L){
    const float* q = p + L*192;
    float d0 = q[jj], d1 = q[HH+jj], d2 = q[2*HH+jj];
    float a  = fsoftplus(d0 + INVF) + EPSF;
    float ps = fmaf(a, Xarr[L], d1);
    float ap = fabsf(ps);
    float E  = fexp(-ap);                 // shared by sigmoid and S (log1p term)
    float R  = frcp(1.0f + E);
    float sg = SIGMOID_FROM_E(ps, E, R);
    // S = logsig(ps)+logsig(-ps)+logc(a) = -ap - 2*log(1+E) + 2eps + log(a)
    float S  = -ap - 2.0f*flog(1.0f + E) + 2.0f*EPSF + flog(a);
    float Ms = wred_max(act ? (d2 + S) : -INFINITY);   // S ~ -300 possible: keep max-sub
    float e  = act ? fexp(d2) : 0.0f;
    float f2 = act ? fexp(d2 + S - Ms) : 0.0f;
    float E0 = wred_sum(e);
    float E1 = wred_sum(e * sg);
    float E2 = wred_sum(f2);
    if (act) mypk[lane] = make_float4(e, e*sg, f2, 0.0f);
    __syncthreads();   // scheduler fence (see note above)
    float t0 = E0, t1 = E1, t2 = E2;
    const uint32_t* Cr = CW + L*MATW + jj*RSW;
#pragma unroll
    for (int t = 0; t < 24; ++t){
      uint32_t cw = Cr[t];
      float c0 = bf_lo(cw), c1 = bf_hi(cw);
      float4 q0 = mypk[2*t], q1 = mypk[2*t+1];
      t0 = fmaf(c0, q0.x, fmaf(c1, q1.x, t0));
      t1 = fmaf(c0, q0.y, fmaf(c1, q1.y, t1));
      t2 = fmaf(c0, q0.z, fmaf(c1, q1.z, t2));
    }
    __syncthreads();
    float xp   = fminf(fmaxf(t1 * frcp(t0), 0.0f), 1.0f);
    float xc   = fmaf(xp, 1.0f - EPSF, 0.5f*EPSF);
    float lsum = flog(xc * (1.0f - xc));          // log(xc)+log(1-xc), single log
    float lj2  = Ms + flog(t2 * frcp(t0));        // LSE_j(logsm_w + S), single log
    float lsep = 0.0f;
    if (L > 0){
      float mp = wred_max(act ? ld : -INFINITY);
      float sm = wred_sum(act ? fexp(ld - mp) : 0.0f);
      lsep = mp + flog(sm);
    }
    ld = lj2 + LOG1MEPS - lsum + lsep;
  }

  // ---- last layer ----
  {
    const float* q = p + 3*192;
    float d0 = q[jj], d1 = q[HH+jj], d2 = q[2*HH+jj], d3 = q[3*HH+jj];
    float e3 = act ? fexp(d3) : 0.0f;
    float xv = ws[128 + b*HH + jj];
    float E30 = wred_sum(e3);
    float E31 = wred_sum(e3 * xv);
    if (act) mypk[lane] = make_float4(e3, e3*xv, 0.0f, 0.0f);
    __syncthreads();
    float s0 = E30, s1 = E31;
    const uint32_t* Ur = CW + 3*MATW + jj*RSW;
#pragma unroll
    for (int t = 0; t < 24; ++t){
      uint32_t cw = Ur[t];
      float c0 = bf_lo(cw), c1 = bf_hi(cw);
      float4 q0 = mypk[2*t], q1 = mypk[2*t+1];
      s0 = fmaf(c0, q0.x, fmaf(c1, q1.x, s0));
      s1 = fmaf(c0, q0.y, fmaf(c1, q1.y, s1));
    }
    float dotx = s1 * frcp(s0);
    float lseu = flog(s0);                    // LSE_k(u[r,k]+d3[k])
    float a  = fsoftplus(d0 + INVF) + EPSF;
    float ps = fmaf(a, dotx, d1);
    float ap = fabsf(ps);
    float E  = fexp(-ap);
    float R  = frcp(1.0f + E);
    float sg = SIGMOID_FROM_E(ps, E, R);
    float Sp = -ap - 2.0f*flog(1.0f + E) + 2.0f*EPSF + flog(a);
    float pw = wl[jj] + d2;
    float ew = act ? fexp(pw) : 0.0f;
    float Z  = wred_sum(ew);
    float xp = fminf(fmaxf(wred_sum(ew * sg) * frcp(Z), 0.0f), 1.0f);
    float lsew = flog(Z);
    float xc   = fmaf(xp, 1.0f - EPSF, 0.5f*EPSF);
    float lsum = flog(xc * (1.0f - xc));
    // c_j = logsm_w[j] + Sp_j - lseu_j ; logj2[k] = d3_k + LSE_j(c_j + u[j,k])
    float c  = (pw - lsew) + Sp - lseu;
    float Mc = wred_max(act ? c : -INFINITY);
    float ec = act ? fexp(c - Mc) : 0.0f;
    float Ec = wred_sum(ec);
    __syncthreads();
    if (act) mypk[lane].x = ec;
    __syncthreads();
    // transposed matvec: lane k: acc = Ec + sum_j ec_j * cU[j][k]
    const uint32_t sh = (jj & 1) ? 0u : 16u;
    const int kw = jj >> 1;
    float acc = Ec;
#pragma unroll 8
    for (int j = 0; j < HH; ++j){
      uint32_t cw = CW[3*MATW + j*RSW + kw];
      float cc = __uint_as_float((cw << sh) & 0xffff0000u);
      acc = fmaf(mypk[j].x, cc, acc);
    }
    float lj2k = d3 + Mc + flog(acc);
    float tot  = act ? (lj2k + LOG1MEPS - lsum + ld) : -INFINITY;
    float Mt = wred_max(tot);
    float sm = wred_sum(act ? fexp(tot - Mt) : 0.0f);
    if (lane == 0) out_ld[gw] = Mt + flog(sm);
  }
}

extern "C" void kernel_launch(void* const* d_in, const int* in_sizes, int n_in,
                              void* d_out, int out_size, void* d_ws, size_t ws_size,
                              hipStream_t stream) {
  const float* params = (const float*)d_in[0];   // (64,256,768)
  const float* xin    = (const float*)d_in[1];   // (64,1)
  // d_in[2] = u_mid: provably unused (softmax over size-1 axis)
  const float* w_mid  = (const float*)d_in[3];   // (3,48,48)
  const float* u_last = (const float*)d_in[4];   // (48,48)
  const float* w_last = (const float*)d_in[5];   // (1,48)
  float* out = (float*)d_out;                    // [64 x] ++ [64*256 logdet]
  float* ws  = (float*)d_ws;                     // [64 X1][64 X2][64*48 xvec2]

  hipLaunchKernelGGL(dsf_xchain, dim3(16), dim3(256), 0, stream,
                     params, xin, w_mid, u_last, w_last, ws, out);
  hipLaunchKernelGGL(dsf_logdet, dim3(4096), dim3(256), 0, stream,
                     params, xin, w_mid, u_last, w_last, ws, out + 64);
}

// Round 13
// 169.472 us; speedup vs baseline: 1.2221x; 1.0512x over previous
//
#include <hip/hip_runtime.h>
#include <math.h>
#include <stdint.h>

#define HH   48
#define RSW  25            // u32 words per packed-bf16 matrix row (24 data + 1 pad)
#define MATW (HH*RSW)      // 1200 u32 per 48x48 matrix

#define EPSF     1e-6f
#define INVF     0.54132327f          // log(exp(1-1e-6)-1)
#define LOG1MEPS (-1.0000005e-6f)     // log(1-1e-6)

static __device__ __forceinline__ float fexp(float x){ return __expf(x); }
static __device__ __forceinline__ float flog(float x){ return __logf(x); }
static __device__ __forceinline__ float frcp(float x){
  float r = __builtin_amdgcn_rcpf(x);
  return r * (2.0f - x * r);          // 1 Newton step; args finite & positive at call sites
}
static __device__ __forceinline__ float wred_max(float v){
#pragma unroll
  for (int m = 32; m; m >>= 1) v = fmaxf(v, __shfl_xor(v, m, 64));
  return v;
}
static __device__ __forceinline__ float wred_sum(float v){
#pragma unroll
  for (int m = 32; m; m >>= 1) v += __shfl_xor(v, m, 64);
  return v;
}
static __device__ __forceinline__ float fsoftplus(float z){
  return fmaxf(z, 0.0f) + flog(1.0f + fexp(-fabsf(z)));
}
static __device__ __forceinline__ uint32_t bf16_rne(float x){
  uint32_t u = __float_as_uint(x);
  return (u + 0x7fffu + ((u >> 16) & 1u)) >> 16;
}
static __device__ __forceinline__ float bf_lo(uint32_t w){ return __uint_as_float(w << 16); }
static __device__ __forceinline__ float bf_hi(uint32_t w){ return __uint_as_float(w & 0xffff0000u); }

// Stage c = exp(w)-1 (packed bf16 pairs). Matvecs use coefficient (1+c): exact in f32
// (bf16 c has 8-bit mantissa at exponent <= -10 -> 1+c needs <= 18 bits). This folds the
// former E-sum wave reductions into the matvec (r12 showed reductions are the stall).
template<int NT>
static __device__ __forceinline__ void init_cmats(uint32_t* CW,
    const float* __restrict__ w_mid, const float* __restrict__ u_last, int tid){
  for (int w = tid; w < 4*HH*24; w += NT){
    int m   = w / (HH*24);
    int rem = w - m*(HH*24);
    int r   = rem / 24, t = rem - r*24;
    const float* src = (m < 3) ? (w_mid + m*HH*HH + r*HH + 2*t)
                               : (u_last + r*HH + 2*t);
    uint32_t b0 = bf16_rne(fexp(src[0]) - 1.0f);
    uint32_t b1 = bf16_rne(fexp(src[1]) - 1.0f);
    CW[m*MATW + r*RSW + t] = b0 | (b1 << 16);
  }
}

// sigmoid via E = exp(-|ps|) <= 1 (no overflow); R = 1/(1+E).
#define SIGMOID_FROM_E(ps, E, R) ( ((ps) >= 0.0f) ? (R) : (E)*(R) )

// ---------------- kernel 1: x-chain (s=0 only), 16 blocks x 4 waves, wave per b ----
__global__ __launch_bounds__(256) void dsf_xchain(
    const float* __restrict__ params, const float* __restrict__ xin,
    const float* __restrict__ w_mid, const float* __restrict__ u_last,
    const float* __restrict__ w_last, float* __restrict__ ws,
    float* __restrict__ out_x)
{
  __shared__ uint32_t CW[4*MATW];
  __shared__ float4 pk[4][HH];

  init_cmats<256>(CW, w_mid, u_last, threadIdx.x);
  __syncthreads();

  const int wid  = threadIdx.x >> 6;
  const int lane = threadIdx.x & 63;
  const int b    = (blockIdx.x << 2) + wid;
  const bool act = lane < HH;
  const int jj   = act ? lane : (HH-1);
  const float* p = params + (size_t)b * 256 * 768;   // s = 0 row
  float4* mypk = pk[wid];

  float X  = xin[b];
  float xn = 0.0f;

#pragma unroll
  for (int L = 0; L < 3; ++L){
    const float* q = p + L*192;
    float d0 = q[jj], d1 = q[HH+jj], d2 = q[2*HH+jj];
    float a  = fsoftplus(d0 + INVF) + EPSF;
    float ps = fmaf(a, X, d1);
    float ap = fabsf(ps);
    float E  = fexp(-ap);
    float R  = frcp(1.0f + E);
    float sg = SIGMOID_FROM_E(ps, E, R);
    float e  = act ? fexp(d2) : 0.0f;
    if (act) mypk[lane] = make_float4(e, e*sg, 0.0f, 0.0f);
    __syncthreads();   // scheduler fence: keeps VGPR bounded (r11: removal -> 120 VGPR)
    float t0 = 0.0f, t1 = 0.0f;
    const uint32_t* Cr = CW + L*MATW + jj*RSW;
#pragma unroll
    for (int t = 0; t < 24; ++t){
      uint32_t cw = Cr[t];
      float c0 = 1.0f + bf_lo(cw), c1 = 1.0f + bf_hi(cw);
      float4 q0 = mypk[2*t], q1 = mypk[2*t+1];
      t0 = fmaf(c0, q0.x, fmaf(c1, q1.x, t0));
      t1 = fmaf(c0, q0.y, fmaf(c1, q1.y, t1));
    }
    __syncthreads();
    float xp = fminf(fmaxf(t1 * frcp(t0), 0.0f), 1.0f);
    float xc = fmaf(xp, 1.0f - EPSF, 0.5f*EPSF);
    xn = flog(xc * frcp(1.0f - xc));
    if (L == 0){ X = wred_sum(act ? xn : 0.0f); if (lane == 0) ws[b] = X; }
    else if (L == 1){ X = wred_sum(act ? xn : 0.0f); if (lane == 0) ws[64 + b] = X; }
    else { if (act) ws[128 + b*HH + lane] = xn; }
  }

  // last layer: x output only
  const float* q = p + 3*192;
  float d0 = q[jj], d1 = q[HH+jj], d2 = q[2*HH+jj], d3 = q[3*HH+jj];
  float e3 = act ? fexp(d3) : 0.0f;
  if (act) mypk[lane] = make_float4(e3, e3*xn, 0.0f, 0.0f);
  __syncthreads();
  float s0 = 0.0f, s1 = 0.0f;
  const uint32_t* Ur = CW + 3*MATW + jj*RSW;
#pragma unroll
  for (int t = 0; t < 24; ++t){
    uint32_t cw = Ur[t];
    float c0 = 1.0f + bf_lo(cw), c1 = 1.0f + bf_hi(cw);
    float4 q0 = mypk[2*t], q1 = mypk[2*t+1];
    s0 = fmaf(c0, q0.x, fmaf(c1, q1.x, s0));
    s1 = fmaf(c0, q0.y, fmaf(c1, q1.y, s1));
  }
  float dotx = s1 * frcp(s0);
  float a  = fsoftplus(d0 + INVF) + EPSF;
  float ps = fmaf(a, dotx, d1);
  float ap = fabsf(ps);
  float E  = fexp(-ap);
  float R  = frcp(1.0f + E);
  float sg = SIGMOID_FROM_E(ps, E, R);
  float pw = w_last[jj] + d2;
  float ew = act ? fexp(pw) : 0.0f;
  float Z  = wred_sum(ew);
  float xp = fminf(fmaxf(wred_sum(ew * sg) * frcp(Z), 0.0f), 1.0f);
  float xc = fmaf(xp, 1.0f - EPSF, 0.5f*EPSF);
  if (lane == 0) out_x[b] = flog(xc * frcp(1.0f - xc));
}

// ---------------- kernel 2: logdet, one wave per (b,s), 4 waves/block -------------
// r12 falsifier: transcendental diet was NEUTRAL at fixed occupancy -> stall-bound on
// serial reduction chains. This round deletes reductions algebraically:
//  - matvec coefficient (1+c) replaces the 3 E-sum reductions per layer (exact in f32)
//  - S in exp-space: exp(S) = a*E*R^2*e^{2eps}; f2 = exp(z-M)*a*R^2, z = d2-ap.
// Mid layer: 6 -> 3 reductions. Last layer: 8 -> 5.
__global__ __launch_bounds__(256) void dsf_logdet(
    const float* __restrict__ params, const float* __restrict__ xin,
    const float* __restrict__ w_mid, const float* __restrict__ u_last,
    const float* __restrict__ w_last, const float* __restrict__ ws,
    float* __restrict__ out_ld)
{
  __shared__ uint32_t CW[4*MATW];   // 19200 B
  __shared__ float4 pk[4][HH];      // 3072 B
  __shared__ float wl[HH];          // ~22.5 KB total

  init_cmats<256>(CW, w_mid, u_last, threadIdx.x);
  if (threadIdx.x < HH) wl[threadIdx.x] = w_last[threadIdx.x];
  __syncthreads();

  const int wid  = threadIdx.x >> 6;
  const int lane = threadIdx.x & 63;
  const int gw   = (blockIdx.x << 2) + wid;   // b*256 + s
  const int b    = gw >> 8;
  const bool act = lane < HH;
  const int jj   = act ? lane : (HH-1);
  const float* p = params + (size_t)gw * 768;
  float4* mypk = pk[wid];

  const float Xarr[3] = { xin[b], ws[b], ws[64 + b] };
  float ld = 0.0f;   // lane r holds logdet entry r

#pragma unroll
  for (int L = 0; L < 3; ++L){
    const float* q = p + L*192;
    float d0 = q[jj], d1 = q[HH+jj], d2 = q[2*HH+jj];
    float a  = fsoftplus(d0 + INVF) + EPSF;
    float ps = fmaf(a, Xarr[L], d1);
    float ap = fabsf(ps);
    float E  = fexp(-ap);
    float R  = frcp(1.0f + E);
    float sg = SIGMOID_FROM_E(ps, E, R);
    float z  = d2 - ap;                        // exponent of exp(d2+S) up to a*R^2 factor
    float M  = wred_max(act ? z : -INFINITY);  // underflow guard (ap can be ~100s)
    float e  = act ? fexp(d2) : 0.0f;
    float g  = act ? fexp(z - M) * (a * (R * R)) : 0.0f;
    if (act) mypk[lane] = make_float4(e, e*sg, g, 0.0f);
    __syncthreads();   // scheduler fence (r11: removal -> 120 VGPR, 21% occ)
    float t0 = 0.0f, t1 = 0.0f, t2 = 0.0f;
    const uint32_t* Cr = CW + L*MATW + jj*RSW;
#pragma unroll
    for (int t = 0; t < 24; ++t){
      uint32_t cw = Cr[t];
      float c0 = 1.0f + bf_lo(cw), c1 = 1.0f + bf_hi(cw);
      float4 q0 = mypk[2*t], q1 = mypk[2*t+1];
      t0 = fmaf(c0, q0.x, fmaf(c1, q1.x, t0));
      t1 = fmaf(c0, q0.y, fmaf(c1, q1.y, t1));
      t2 = fmaf(c0, q0.z, fmaf(c1, q1.z, t2));
    }
    __syncthreads();
    float xp   = fminf(fmaxf(t1 * frcp(t0), 0.0f), 1.0f);
    float xc   = fmaf(xp, 1.0f - EPSF, 0.5f*EPSF);
    float lsum = flog(xc * (1.0f - xc));
    float lj2  = M + 2.0f*EPSF + flog(t2 * frcp(t0));   // LSE_j(logsm_w + S)
    float lsep = 0.0f;
    if (L > 0){
      float mp = wred_max(act ? ld : -INFINITY);
      float sm = wred_sum(act ? fexp(ld - mp) : 0.0f);
      lsep = mp + flog(sm);
    }
    ld = lj2 + LOG1MEPS - lsum + lsep;
  }

  // ---- last layer ----
  {
    const float* q = p + 3*192;
    float d0 = q[jj], d1 = q[HH+jj], d2 = q[2*HH+jj], d3 = q[3*HH+jj];
    float e3 = act ? fexp(d3) : 0.0f;
    float xv = ws[128 + b*HH + jj];
    if (act) mypk[lane] = make_float4(e3, e3*xv, 0.0f, 0.0f);
    __syncthreads();
    float s0 = 0.0f, s1 = 0.0f;
    const uint32_t* Ur = CW + 3*MATW + jj*RSW;
#pragma unroll
    for (int t = 0; t < 24; ++t){
      uint32_t cw = Ur[t];
      float c0 = 1.0f + bf_lo(cw), c1 = 1.0f + bf_hi(cw);
      float4 q0 = mypk[2*t], q1 = mypk[2*t+1];
      s0 = fmaf(c0, q0.x, fmaf(c1, q1.x, s0));
      s1 = fmaf(c0, q0.y, fmaf(c1, q1.y, s1));
    }
    float dotx = s1 * frcp(s0);
    float lseu = flog(s0);                    // LSE_k(u[r,k]+d3[k])  (per-lane row r)
    float a  = fsoftplus(d0 + INVF) + EPSF;
    float ps = fmaf(a, dotx, d1);
    float ap = fabsf(ps);
    float E  = fexp(-ap);
    float R  = frcp(1.0f + E);
    float sg = SIGMOID_FROM_E(ps, E, R);
    float pw = wl[jj] + d2;
    float ew = act ? fexp(pw) : 0.0f;
    float Z  = wred_sum(ew);
    float xp = fminf(fmaxf(wred_sum(ew * sg) * frcp(Z), 0.0f), 1.0f);
    float lsew = flog(Z);
    float xc   = fmaf(xp, 1.0f - EPSF, 0.5f*EPSF);
    float lsum = flog(xc * (1.0f - xc));
    // c_j = pw + Sp - lseu - lsew ; exp-space: ec = exp(y-My)*a*R^2, y = pw - ap - lseu
    float y  = pw - ap - lseu;
    float My = wred_max(act ? y : -INFINITY);
    float ec = act ? fexp(y - My) * (a * (R * R)) : 0.0f;
    __syncthreads();
    if (act) mypk[lane].x = ec;
    __syncthreads();
    // transposed matvec: lane k: acc = sum_j (1+cU[j][k]) * ec_j
    const uint32_t sh = (jj & 1) ? 0u : 16u;
    const int kw = jj >> 1;
    float acc = 0.0f;
#pragma unroll 8
    for (int j = 0; j < HH; ++j){
      uint32_t cw = CW[3*MATW + j*RSW + kw];
      float cc = 1.0f + __uint_as_float((cw << sh) & 0xffff0000u);
      acc = fmaf(mypk[j].x, cc, acc);
    }
    float lj2k = d3 + My + 2.0f*EPSF - lsew + flog(acc);
    float tot  = act ? (lj2k + LOG1MEPS - lsum + ld) : -INFINITY;
    float Mt = wred_max(tot);
    float sm = wred_sum(act ? fexp(tot - Mt) : 0.0f);
    if (lane == 0) out_ld[gw] = Mt + flog(sm);
  }
}

extern "C" void kernel_launch(void* const* d_in, const int* in_sizes, int n_in,
                              void* d_out, int out_size, void* d_ws, size_t ws_size,
                              hipStream_t stream) {
  const float* params = (const float*)d_in[0];   // (64,256,768)
  const float* xin    = (const float*)d_in[1];   // (64,1)
  // d_in[2] = u_mid: provably unused (softmax over size-1 axis)
  const float* w_mid  = (const float*)d_in[3];   // (3,48,48)
  const float* u_last = (const float*)d_in[4];   // (48,48)
  const float* w_last = (const float*)d_in[5];   // (1,48)
  float* out = (float*)d_out;                    // [64 x] ++ [64*256 logdet]
  float* ws  = (float*)d_ws;                     // [64 X1][64 X2][64*48 xvec2]

  hipLaunchKernelGGL(dsf_xchain, dim3(16), dim3(256), 0, stream,
                     params, xin, w_mid, u_last, w_last, ws, out);
  hipLaunchKernelGGL(dsf_logdet, dim3(4096), dim3(256), 0, stream,
                     params, xin, w_mid, u_last, w_last, ws, out + 64);
}

// Round 14
// 166.773 us; speedup vs baseline: 1.2419x; 1.0162x over previous
//
#include <hip/hip_runtime.h>
#include <math.h>
#include <stdint.h>

#define HH 48

// ---- legacy layout for xchain kernel (unchanged, f32-exact) ----
#define RSW  25
#define MATW (HH*RSW)

#define EPSF     1e-6f
#define INVF     0.54132327f          // log(exp(1-1e-6)-1)
#define LOG1MEPS (-1.0000005e-6f)     // log(1-1e-6)

typedef float  f32x4  __attribute__((ext_vector_type(4)));
typedef short  bf16x8 __attribute__((ext_vector_type(8)));

static __device__ __forceinline__ float fexp(float x){ return __expf(x); }
static __device__ __forceinline__ float flog(float x){ return __logf(x); }
static __device__ __forceinline__ float frcp(float x){
  float r = __builtin_amdgcn_rcpf(x);
  return r * (2.0f - x * r);
}
static __device__ __forceinline__ float wred_max(float v){
#pragma unroll
  for (int m = 32; m; m >>= 1) v = fmaxf(v, __shfl_xor(v, m, 64));
  return v;
}
static __device__ __forceinline__ float wred_sum(float v){
#pragma unroll
  for (int m = 32; m; m >>= 1) v += __shfl_xor(v, m, 64);
  return v;
}
static __device__ __forceinline__ float fsoftplus(float z){
  return fmaxf(z, 0.0f) + flog(1.0f + fexp(-fabsf(z)));
}
static __device__ __forceinline__ uint32_t bf16_rne(float x){
  uint32_t u = __float_as_uint(x);
  return (u + 0x7fffu + ((u >> 16) & 1u)) >> 16;
}
static __device__ __forceinline__ float bf_lo(uint32_t w){ return __uint_as_float(w << 16); }
static __device__ __forceinline__ float bf_hi(uint32_t w){ return __uint_as_float(w & 0xffff0000u); }
static __device__ __forceinline__ bf16x8 frag_words(uint32_t w0,uint32_t w1,uint32_t w2,uint32_t w3){
  union { uint32_t w[4]; bf16x8 v; } u; u.w[0]=w0; u.w[1]=w1; u.w[2]=w2; u.w[3]=w3; return u.v;
}

#define SIGMOID_FROM_E(ps, E, R) ( ((ps) >= 0.0f) ? (R) : (E)*(R) )

// =============== kernel 1: x-chain (s=0 only) — unchanged r13 f32-exact path ======
template<int NT>
static __device__ __forceinline__ void init_cmats(uint32_t* CW,
    const float* __restrict__ w_mid, const float* __restrict__ u_last, int tid){
  for (int w = tid; w < 4*HH*24; w += NT){
    int m   = w / (HH*24);
    int rem = w - m*(HH*24);
    int r   = rem / 24, t = rem - r*24;
    const float* src = (m < 3) ? (w_mid + m*HH*HH + r*HH + 2*t)
                               : (u_last + r*HH + 2*t);
    uint32_t b0 = bf16_rne(fexp(src[0]) - 1.0f);
    uint32_t b1 = bf16_rne(fexp(src[1]) - 1.0f);
    CW[m*MATW + r*RSW + t] = b0 | (b1 << 16);
  }
}

__global__ __launch_bounds__(256) void dsf_xchain(
    const float* __restrict__ params, const float* __restrict__ xin,
    const float* __restrict__ w_mid, const float* __restrict__ u_last,
    const float* __restrict__ w_last, float* __restrict__ ws,
    float* __restrict__ out_x)
{
  __shared__ uint32_t CW[4*MATW];
  __shared__ float4 pk[4][HH];

  init_cmats<256>(CW, w_mid, u_last, threadIdx.x);
  __syncthreads();

  const int wid  = threadIdx.x >> 6;
  const int lane = threadIdx.x & 63;
  const int b    = (blockIdx.x << 2) + wid;
  const bool act = lane < HH;
  const int jj   = act ? lane : (HH-1);
  const float* p = params + (size_t)b * 256 * 768;
  float4* mypk = pk[wid];

  float X  = xin[b];
  float xn = 0.0f;

#pragma unroll
  for (int L = 0; L < 3; ++L){
    const float* q = p + L*192;
    float d0 = q[jj], d1 = q[HH+jj], d2 = q[2*HH+jj];
    float a  = fsoftplus(d0 + INVF) + EPSF;
    float ps = fmaf(a, X, d1);
    float ap = fabsf(ps);
    float E  = fexp(-ap);
    float R  = frcp(1.0f + E);
    float sg = SIGMOID_FROM_E(ps, E, R);
    float e  = act ? fexp(d2) : 0.0f;
    if (act) mypk[lane] = make_float4(e, e*sg, 0.0f, 0.0f);
    __syncthreads();
    float t0 = 0.0f, t1 = 0.0f;
    const uint32_t* Cr = CW + L*MATW + jj*RSW;
#pragma unroll
    for (int t = 0; t < 24; ++t){
      uint32_t cw = Cr[t];
      float c0 = 1.0f + bf_lo(cw), c1 = 1.0f + bf_hi(cw);
      float4 q0 = mypk[2*t], q1 = mypk[2*t+1];
      t0 = fmaf(c0, q0.x, fmaf(c1, q1.x, t0));
      t1 = fmaf(c0, q0.y, fmaf(c1, q1.y, t1));
    }
    __syncthreads();
    float xp = fminf(fmaxf(t1 * frcp(t0), 0.0f), 1.0f);
    float xc = fmaf(xp, 1.0f - EPSF, 0.5f*EPSF);
    xn = flog(xc * frcp(1.0f - xc));
    if (L == 0){ X = wred_sum(act ? xn : 0.0f); if (lane == 0) ws[b] = X; }
    else if (L == 1){ X = wred_sum(act ? xn : 0.0f); if (lane == 0) ws[64 + b] = X; }
    else { if (act) ws[128 + b*HH + lane] = xn; }
  }

  const float* q = p + 3*192;
  float d0 = q[jj], d1 = q[HH+jj], d2 = q[2*HH+jj], d3 = q[3*HH+jj];
  float e3 = act ? fexp(d3) : 0.0f;
  if (act) mypk[lane] = make_float4(e3, e3*xn, 0.0f, 0.0f);
  __syncthreads();
  float s0 = 0.0f, s1 = 0.0f;
  const uint32_t* Ur = CW + 3*MATW + jj*RSW;
#pragma unroll
  for (int t = 0; t < 24; ++t){
    uint32_t cw = Ur[t];
    float c0 = 1.0f + bf_lo(cw), c1 = 1.0f + bf_hi(cw);
    float4 q0 = mypk[2*t], q1 = mypk[2*t+1];
    s0 = fmaf(c0, q0.x, fmaf(c1, q1.x, s0));
    s1 = fmaf(c0, q0.y, fmaf(c1, q1.y, s1));
  }
  float dotx = s1 * frcp(s0);
  float a  = fsoftplus(d0 + INVF) + EPSF;
  float ps = fmaf(a, dotx, d1);
  float ap = fabsf(ps);
  float E  = fexp(-ap);
  float R  = frcp(1.0f + E);
  float sg = SIGMOID_FROM_E(ps, E, R);
  float pw = w_last[jj] + d2;
  float ew = act ? fexp(pw) : 0.0f;
  float Z  = wred_sum(ew);
  float xp = fminf(fmaxf(wred_sum(ew * sg) * frcp(Z), 0.0f), 1.0f);
  float xc = fmaf(xp, 1.0f - EPSF, 0.5f*EPSF);
  if (lane == 0) out_x[b] = flog(xc * frcp(1.0f - xc));
}

// =============== kernel 2: logdet — MFMA matvec engine ============================
// Per block (4 pairs): T[48r x 16n] = c[48x48] . P[48k x 16n] via mfma_f32_16x16x32_bf16
//   waves 0..2 own M-tiles (rows 16w..16w+15); wave 3 computes row-sums with a ones-A
//   tile (exact split: T_full = Sum_j P_j + Sum_j c_j P_j ; bf16(1+c)==1.0 would lose c).
// Cols n = pair*3 + {0:e*sg, 1:e*(1-sg), 2:g}; t0 = t1+t1m kills the 1-xp cancellation.
// A-frag layout (16x16x32): lane holds A[row=l&15][k=ks*32+(l>>4)*8+e], e=0..7.
// B-frag:                   lane holds B[k=ks*32+(l>>4)*8+e][col=l&15].
// D (m89-verified):         lane holds D[row=(l>>4)*4+reg][col=l&15].
#define AFW (5*3*2*64*4)   // 5 mats (3 w_mid, u_last, u_last^T) x 3 Mtiles x 2 Ksteps
#define PBS 36             // u32 stride of a Pb row = 72 bf16 (144B, 16B-aligned)
#define TBS 17             // f32 stride of Tb row

__global__ __launch_bounds__(256) void dsf_logdet(
    const float* __restrict__ params, const float* __restrict__ xin,
    const float* __restrict__ w_mid, const float* __restrict__ u_last,
    const float* __restrict__ w_last, const float* __restrict__ ws,
    float* __restrict__ out_ld)
{
  __shared__ __align__(16) uint32_t AF[AFW];    // 30720 B
  __shared__ __align__(16) uint32_t Pb[16*PBS]; //  2304 B
  __shared__ float Tb[48*TBS];                  //  3264 B
  __shared__ float RS[16];
  __shared__ float wl[HH];                      // total ~35.7 KB -> 4 blocks/CU

  // ---- init: A-fragments of c = exp(w)-1 (bf16), zero-padded k>=48 ----
  for (int idx = threadIdx.x; idx < AFW; idx += 256){
    int uw   = idx & 3;
    int lane = (idx >> 2) & 63;
    int ks   = (idx >> 8) & 1;
    int mtm  = idx >> 9;            // 0..14
    int mt   = mtm % 3, mat = mtm / 3;
    int row  = mt*16 + (lane & 15);
    int kb   = ks*32 + ((lane >> 4) << 3) + uw*2;
    float v0 = 0.0f, v1 = 0.0f;
    if (kb < 48){
      const float* src;
      if (mat < 3)      src = w_mid + mat*HH*HH + row*HH;
      else if (mat == 3) src = u_last + row*HH;
      else               src = u_last;               // transposed: [k][row]
      v0 = (mat == 4) ? fexp(src[kb*HH + row]) - 1.0f : fexp(src[kb]) - 1.0f;
      if (kb + 1 < 48)
        v1 = (mat == 4) ? fexp(src[(kb+1)*HH + row]) - 1.0f : fexp(src[kb+1]) - 1.0f;
    }
    AF[idx] = bf16_rne(v0) | (bf16_rne(v1) << 16);
  }
  for (int idx = threadIdx.x; idx < 16*PBS; idx += 256) Pb[idx] = 0;   // zero incl. k>=48, n>=12
  if (threadIdx.x < HH) wl[threadIdx.x] = w_last[threadIdx.x];
  __syncthreads();

  const int wid  = threadIdx.x >> 6;
  const int lane = threadIdx.x & 63;
  const int gw   = (blockIdx.x << 2) + wid;
  const int b    = gw >> 8;
  const bool act = lane < HH;
  const int jj   = act ? lane : (HH-1);
  const float* p = params + (size_t)gw * 768;
  const int n0   = wid * 3;
  uint16_t* Pb16 = (uint16_t*)Pb;

  const int colB   = lane & 15;
  const int kgrp4  = (lane >> 4) << 2;        // u32 offset of this lane's 8-bf16 k-chunk
  const int rowD0  = (lane >> 4) << 2;        // D rows within tile
  const uint32_t onesw = 0x3F803F80u;
  const bf16x8 onesA0 = frag_words(onesw, onesw, onesw, onesw);
  const uint32_t hw = (lane < 32) ? onesw : 0u;
  const bf16x8 onesA1 = frag_words(hw, hw, hw, hw);

  const float Xarr[3] = { xin[b], ws[b], ws[64 + b] };
  float ld = 0.0f;

#pragma unroll
  for (int L = 0; L < 3; ++L){
    const float* q = p + L*192;
    float d0 = q[jj], d1 = q[HH+jj], d2 = q[2*HH+jj];
    float a  = fsoftplus(d0 + INVF) + EPSF;
    float ps = fmaf(a, Xarr[L], d1);
    float ap = fabsf(ps);
    float E  = fexp(-ap);
    float R  = frcp(1.0f + E);
    float sg  = SIGMOID_FROM_E(ps, E, R);
    float sgm = (ps >= 0.0f) ? E*R : R;       // sigmoid(-ps), stable
    float z  = d2 - ap;
    float M  = wred_max(act ? z : -INFINITY);
    float e  = fexp(d2);
    float g  = fexp(z - M) * (a * (R * R));
    if (act){
      Pb16[(n0+0)*(2*PBS) + jj] = (uint16_t)bf16_rne(e*sg);
      Pb16[(n0+1)*(2*PBS) + jj] = (uint16_t)bf16_rne(e*sgm);
      Pb16[(n0+2)*(2*PBS) + jj] = (uint16_t)bf16_rne(g);
    }
    __syncthreads();
    // ---- MFMA: T_resid = c . P ; wave3: rowsums via ones-A ----
    {
      f32x4 acc = {0.f,0.f,0.f,0.f};
      const bf16x8 b0 = *(const bf16x8*)&Pb[colB*PBS + kgrp4];
      const bf16x8 b1 = *(const bf16x8*)&Pb[colB*PBS + 16 + kgrp4];
      if (wid < 3){
        const int base = ((L*3 + wid)*2)*256 + lane*4;
        const bf16x8 a0 = *(const bf16x8*)&AF[base];
        const bf16x8 a1 = *(const bf16x8*)&AF[base + 256];
        acc = __builtin_amdgcn_mfma_f32_16x16x32_bf16(a0, b0, acc, 0,0,0);
        acc = __builtin_amdgcn_mfma_f32_16x16x32_bf16(a1, b1, acc, 0,0,0);
        const int r0 = wid*16 + rowD0;
        Tb[(r0+0)*TBS + colB] = acc[0];
        Tb[(r0+1)*TBS + colB] = acc[1];
        Tb[(r0+2)*TBS + colB] = acc[2];
        Tb[(r0+3)*TBS + colB] = acc[3];
      } else {
        acc = __builtin_amdgcn_mfma_f32_16x16x32_bf16(onesA0, b0, acc, 0,0,0);
        acc = __builtin_amdgcn_mfma_f32_16x16x32_bf16(onesA1, b1, acc, 0,0,0);
        if (lane < 16) RS[lane] = acc[0];     // row 0 = column sums
      }
    }
    __syncthreads();
    float t1  = RS[n0+0] + Tb[jj*TBS + n0+0];
    float t1m = RS[n0+1] + Tb[jj*TBS + n0+1];
    float t2  = RS[n0+2] + Tb[jj*TBS + n0+2];
    float t0  = t1 + t1m;
    float rt0 = frcp(t0);
    float xp  = fminf(fmaxf(t1 *rt0, 0.0f), 1.0f);
    float xpm = fminf(fmaxf(t1m*rt0, 0.0f), 1.0f);
    float xc  = fmaf(xp , 1.0f - EPSF, 0.5f*EPSF);
    float xcm = fmaf(xpm, 1.0f - EPSF, 0.5f*EPSF);
    float lsum = flog(xc * xcm);
    float lj2  = M + 2.0f*EPSF + flog(t2 * rt0);
    float lsep = 0.0f;
    if (L > 0){
      float mp = wred_max(act ? ld : -INFINITY);
      float sm = wred_sum(act ? fexp(ld - mp) : 0.0f);
      lsep = mp + flog(sm);
    }
    ld = lj2 + LOG1MEPS - lsum + lsep;
  }

  // ---- last layer ----
  {
    const float* q = p + 3*192;
    float d0 = q[jj], d1 = q[HH+jj], d2 = q[2*HH+jj], d3 = q[3*HH+jj];
    float e3 = fexp(d3);
    float xv = ws[128 + b*HH + jj];
    if (act){
      Pb16[(n0+0)*(2*PBS) + jj] = (uint16_t)bf16_rne(e3);
      Pb16[(n0+1)*(2*PBS) + jj] = (uint16_t)bf16_rne(e3*xv);
    }
    __syncthreads();
    {
      f32x4 acc = {0.f,0.f,0.f,0.f};
      const bf16x8 b0 = *(const bf16x8*)&Pb[colB*PBS + kgrp4];
      const bf16x8 b1 = *(const bf16x8*)&Pb[colB*PBS + 16 + kgrp4];
      if (wid < 3){
        const int base = ((3*3 + wid)*2)*256 + lane*4;   // mat 3 = u_last
        const bf16x8 a0 = *(const bf16x8*)&AF[base];
        const bf16x8 a1 = *(const bf16x8*)&AF[base + 256];
        acc = __builtin_amdgcn_mfma_f32_16x16x32_bf16(a0, b0, acc, 0,0,0);
        acc = __builtin_amdgcn_mfma_f32_16x16x32_bf16(a1, b1, acc, 0,0,0);
        const int r0 = wid*16 + rowD0;
        Tb[(r0+0)*TBS + colB] = acc[0];
        Tb[(r0+1)*TBS + colB] = acc[1];
        Tb[(r0+2)*TBS + colB] = acc[2];
        Tb[(r0+3)*TBS + colB] = acc[3];
      } else {
        acc = __builtin_amdgcn_mfma_f32_16x16x32_bf16(onesA0, b0, acc, 0,0,0);
        acc = __builtin_amdgcn_mfma_f32_16x16x32_bf16(onesA1, b1, acc, 0,0,0);
        if (lane < 16) RS[lane] = acc[0];
      }
    }
    __syncthreads();
    float s0 = RS[n0+0] + Tb[jj*TBS + n0+0];
    float s1 = RS[n0+1] + Tb[jj*TBS + n0+1];
    float dotx = s1 * frcp(s0);
    float lseu = flog(s0);
    float a  = fsoftplus(d0 + INVF) + EPSF;
    float ps = fmaf(a, dotx, d1);
    float ap = fabsf(ps);
    float E  = fexp(-ap);
    float R  = frcp(1.0f + E);
    float sg  = SIGMOID_FROM_E(ps, E, R);
    float sgm = (ps >= 0.0f) ? E*R : R;
    float pw = wl[jj] + d2;
    float ew  = act ? fexp(pw) : 0.0f;
    float Z   = wred_sum(ew);
    float S1  = wred_sum(ew * sg);
    float S1m = wred_sum(ew * sgm);
    float rZ  = frcp(Z);
    float xp  = fminf(fmaxf(S1 *rZ, 0.0f), 1.0f);
    float xpm = fminf(fmaxf(S1m*rZ, 0.0f), 1.0f);
    float lsew = flog(Z);
    float xc  = fmaf(xp , 1.0f - EPSF, 0.5f*EPSF);
    float xcm = fmaf(xpm, 1.0f - EPSF, 0.5f*EPSF);
    float lsum = flog(xc * xcm);
    float y  = pw - ap - lseu;
    float My = wred_max(act ? y : -INFINITY);
    float ec = fexp(y - My) * (a * (R * R));
    if (act) Pb16[n0*(2*PBS) + jj] = (uint16_t)bf16_rne(ec);
    __syncthreads();
    // acc_r = sum_j (1+cU[j][r]) ec_j  via mat 4 = u_last^T (+ rowsum)
    {
      f32x4 acc = {0.f,0.f,0.f,0.f};
      const bf16x8 b0 = *(const bf16x8*)&Pb[colB*PBS + kgrp4];
      const bf16x8 b1 = *(const bf16x8*)&Pb[colB*PBS + 16 + kgrp4];
      if (wid < 3){
        const int base = ((4*3 + wid)*2)*256 + lane*4;   // mat 4 = u_last^T
        const bf16x8 a0 = *(const bf16x8*)&AF[base];
        const bf16x8 a1 = *(const bf16x8*)&AF[base + 256];
        acc = __builtin_amdgcn_mfma_f32_16x16x32_bf16(a0, b0, acc, 0,0,0);
        acc = __builtin_amdgcn_mfma_f32_16x16x32_bf16(a1, b1, acc, 0,0,0);
        const int r0 = wid*16 + rowD0;
        Tb[(r0+0)*TBS + colB] = acc[0];
        Tb[(r0+1)*TBS + colB] = acc[1];
        Tb[(r0+2)*TBS + colB] = acc[2];
        Tb[(r0+3)*TBS + colB] = acc[3];
      } else {
        acc = __builtin_amdgcn_mfma_f32_16x16x32_bf16(onesA0, b0, acc, 0,0,0);
        acc = __builtin_amdgcn_mfma_f32_16x16x32_bf16(onesA1, b1, acc, 0,0,0);
        if (lane < 16) RS[lane] = acc[0];
      }
    }
    __syncthreads();
    float accr = RS[n0] + Tb[jj*TBS + n0];
    float lj2k = d3 + My + 2.0f*EPSF - lsew + flog(accr);
    float tot  = act ? (lj2k + LOG1MEPS - lsum + ld) : -INFINITY;
    float Mt = wred_max(tot);
    float sm = wred_sum(act ? fexp(tot - Mt) : 0.0f);
    if (lane == 0) out_ld[gw] = Mt + flog(sm);
  }
}

extern "C" void kernel_launch(void* const* d_in, const int* in_sizes, int n_in,
                              void* d_out, int out_size, void* d_ws, size_t ws_size,
                              hipStream_t stream) {
  const float* params = (const float*)d_in[0];   // (64,256,768)
  const float* xin    = (const float*)d_in[1];   // (64,1)
  // d_in[2] = u_mid: provably unused (softmax over size-1 axis)
  const float* w_mid  = (const float*)d_in[3];   // (3,48,48)
  const float* u_last = (const float*)d_in[4];   // (48,48)
  const float* w_last = (const float*)d_in[5];   // (1,48)
  float* out = (float*)d_out;                    // [64 x] ++ [64*256 logdet]
  float* ws  = (float*)d_ws;                     // [64 X1][64 X2][64*48 xvec2]

  hipLaunchKernelGGL(dsf_xchain, dim3(16), dim3(256), 0, stream,
                     params, xin, w_mid, u_last, w_last, ws, out);
  hipLaunchKernelGGL(dsf_logdet, dim3(4096), dim3(256), 0, stream,
                     params, xin, w_mid, u_last, w_last, ws, out + 64);
}